// Round 3
// baseline (498.246 us; speedup 1.0000x reference)
//
#include <hip/hip_runtime.h>

// PairDistanceLoss: loss_i = (sum_{y=1} exp(x)) * (sum_{y=0} exp(-x)) / (ni*(C-ni))
// output = mean_i loss_i (fp32 scalar). N=16384 rows, C=4096 cols.
//
// R2 post-mortem: 162us @ 20% HBM, VALUBusy 10% -> latency-bound; loads drain
// while the wave computes. Fix: one row per wave, explicit double-buffered
// register pipeline (prefetch chunk k+1 during compute of chunk k), pipe
// primed 2 chunks deep. y is L3-resident (FETCH==x only), floor ~50us.

#define C_DIM 4096
#define BLOCK 256
#define WPB   (BLOCK / 64)   // waves per block = 4

__global__ __launch_bounds__(BLOCK) void pdl_rows(const float* __restrict__ x,
                                                  const int* __restrict__ y,
                                                  float* __restrict__ partial) {
    const int lane = threadIdx.x & 63;
    const int wave = threadIdx.x >> 6;
    const int row  = blockIdx.x * WPB + wave;

    const float4* __restrict__ x4 = (const float4*)(x + (size_t)row * C_DIM);
    const int4*  __restrict__ y4 = (const int4*)(y + (size_t)row * C_DIM);

    float pos = 0.0f, neg = 0.0f;
    int cnt = 0;

    // 4096 elems / 64 lanes / 4 = 16 float4-loads per lane, in 4 chunks of 4.
    float4 xa[4], xb[4];
    int4  ya[4], yb[4];

    auto prefetch = [&](float4 (&xv)[4], int4 (&yv)[4], int c) {
#pragma unroll
        for (int u = 0; u < 4; ++u) {
            const int i = lane + (c * 4 + u) * 64;
            xv[u] = x4[i];
            yv[u] = y4[i];
        }
    };
    auto compute = [&](const float4 (&xv)[4], const int4 (&yv)[4]) {
#pragma unroll
        for (int u = 0; u < 4; ++u) {
            { const float e = __expf(yv[u].x ? xv[u].x : -xv[u].x);
              pos += yv[u].x ? e : 0.0f; neg += yv[u].x ? 0.0f : e; cnt += yv[u].x; }
            { const float e = __expf(yv[u].y ? xv[u].y : -xv[u].y);
              pos += yv[u].y ? e : 0.0f; neg += yv[u].y ? 0.0f : e; cnt += yv[u].y; }
            { const float e = __expf(yv[u].z ? xv[u].z : -xv[u].z);
              pos += yv[u].z ? e : 0.0f; neg += yv[u].z ? 0.0f : e; cnt += yv[u].z; }
            { const float e = __expf(yv[u].w ? xv[u].w : -xv[u].w);
              pos += yv[u].w ? e : 0.0f; neg += yv[u].w ? 0.0f : e; cnt += yv[u].w; }
        }
    };

    // software pipeline, primed two chunks deep: loads stay in flight
    // across every compute phase.
    prefetch(xa, ya, 0);
    prefetch(xb, yb, 1);
    compute(xa, ya);          // waits only on chunk0; chunk1 in flight
    prefetch(xa, ya, 2);
    compute(xb, yb);          // chunk2 in flight
    prefetch(xb, yb, 3);
    compute(xa, ya);          // chunk3 in flight
    compute(xb, yb);

    // wave-64 reduction: lane 0 ends with the row totals
#pragma unroll
    for (int off = 32; off >= 1; off >>= 1) {
        pos += __shfl_down(pos, off, 64);
        neg += __shfl_down(neg, off, 64);
        cnt += __shfl_down(cnt, off, 64);
    }

    __shared__ float sacc[WPB];
    if (lane == 0) {
        const float denom = (float)cnt * (float)(C_DIM - cnt);
        sacc[wave] = (pos * neg) / denom;
    }
    __syncthreads();
    if (threadIdx.x == 0) {
        float b = 0.0f;
#pragma unroll
        for (int w = 0; w < WPB; ++w) b += sacc[w];
        partial[blockIdx.x] = b;  // plain store, no atomic
    }
}

__global__ __launch_bounds__(BLOCK) void pdl_reduce(const float* __restrict__ partial,
                                                    float* __restrict__ out,
                                                    int n_partial, float inv_n) {
    const float4* p4 = (const float4*)partial;
    float s = 0.0f;
    for (int i = threadIdx.x; i < n_partial / 4; i += BLOCK) {
        const float4 v = p4[i];
        s += (v.x + v.y) + (v.z + v.w);
    }
#pragma unroll
    for (int off = 32; off >= 1; off >>= 1) s += __shfl_down(s, off, 64);
    __shared__ float sw[WPB];
    const int lane = threadIdx.x & 63;
    const int wave = threadIdx.x >> 6;
    if (lane == 0) sw[wave] = s;
    __syncthreads();
    if (threadIdx.x == 0) {
        float t = 0.0f;
#pragma unroll
        for (int w = 0; w < WPB; ++w) t += sw[w];
        out[0] = t * inv_n;
    }
}

extern "C" void kernel_launch(void* const* d_in, const int* in_sizes, int n_in,
                              void* d_out, int out_size, void* d_ws, size_t ws_size,
                              hipStream_t stream) {
    const float* x = (const float*)d_in[0];
    const int*   y = (const int*)d_in[1];
    float* out = (float*)d_out;
    float* partial = (float*)d_ws;  // n_blocks floats, fully rewritten each call

    const int n_rows  = in_sizes[0] / C_DIM;  // 16384
    const int n_blocks = n_rows / WPB;        // 4096

    pdl_rows<<<n_blocks, BLOCK, 0, stream>>>(x, y, partial);
    pdl_reduce<<<1, BLOCK, 0, stream>>>(partial, out, n_blocks, 1.0f / (float)n_rows);
}

// Round 4
// 469.668 us; speedup vs baseline: 1.0608x; 1.0608x over previous
//
#include <hip/hip_runtime.h>

// PairDistanceLoss: loss_i = (sum_{y=1} exp(x)) * (sum_{y=0} exp(-x)) / (ni*(C-ni))
// output = mean_i loss_i (fp32 scalar). N=16384 rows, C=4096 cols.
//
// R3 post-mortem: per-wave pipelining NEUTRAL (~165us). All observed read
// streams (our kernel 3.3 TB/s, d2d restore ~3.1, m13 copy read-side 3.15)
// converge at ~3.2 TB/s => per-CU read-path limit (~64-entry L1 miss queue:
// 5.4 B/cyc/CU * ~700cyc latency = ~59 lines in flight). R4 levers:
// nontemporal loads (bypass L1 alloc) + cross-row sustained pipeline.

typedef float v4f __attribute__((ext_vector_type(4)));
typedef int   v4i __attribute__((ext_vector_type(4)));

#define C_DIM 4096
#define BLOCK 256
#define NBLK  2048
#define WPB   (BLOCK / 64)       // 4 waves per block
#define RPW   2                  // rows per wave: 16384 / (2048*4)

__global__ __launch_bounds__(BLOCK) void pdl_rows(const float* __restrict__ x,
                                                  const int* __restrict__ y,
                                                  float* __restrict__ partial) {
    const int lane  = threadIdx.x & 63;
    const int wave  = threadIdx.x >> 6;
    const int gwave = blockIdx.x * WPB + wave;
    const int rbase = gwave * RPW;

    float pos = 0.0f, neg = 0.0f;
    int cnt = 0;
    float wacc = 0.0f;  // lane-0 row results

    v4f xa[4], xb[4];
    v4i ya[4], yb[4];

    // global chunk id c in [0, RPW*4): row = rbase + c/4, intra-row chunk c&3
    auto prefetch = [&](v4f (&xv)[4], v4i (&yv)[4], int c) {
        const size_t rowoff = (size_t)(rbase + (c >> 2)) * C_DIM;
        const v4f* __restrict__ x4 = (const v4f*)(x + rowoff);
        const v4i* __restrict__ y4 = (const v4i*)(y + rowoff);
#pragma unroll
        for (int u = 0; u < 4; ++u) {
            const int i = lane + ((c & 3) * 4 + u) * 64;
            xv[u] = __builtin_nontemporal_load(x4 + i);
            yv[u] = __builtin_nontemporal_load(y4 + i);
        }
    };
    auto compute = [&](const v4f (&xv)[4], const v4i (&yv)[4]) {
#pragma unroll
        for (int u = 0; u < 4; ++u) {
#pragma unroll
            for (int e = 0; e < 4; ++e) {
                const int   yy = yv[u][e];
                const float xx = xv[u][e];
                const float ex = __expf(yy ? xx : -xx);
                pos += yy ? ex : 0.0f;
                neg += yy ? 0.0f : ex;
                cnt += yy;
            }
        }
    };
    auto finish_row = [&]() {
#pragma unroll
        for (int off = 32; off >= 1; off >>= 1) {
            pos += __shfl_down(pos, off, 64);
            neg += __shfl_down(neg, off, 64);
            cnt += __shfl_down(cnt, off, 64);
        }
        if (lane == 0) {
            const float denom = (float)cnt * (float)(C_DIM - cnt);
            wacc += (pos * neg) / denom;
        }
        pos = 0.0f; neg = 0.0f; cnt = 0;
    };

    // sustained 2-deep pipeline across both rows (no drain at row boundary)
    prefetch(xa, ya, 0);
    prefetch(xb, yb, 1);
    compute(xa, ya);  prefetch(xa, ya, 2);
    compute(xb, yb);  prefetch(xb, yb, 3);
    compute(xa, ya);  prefetch(xa, ya, 4);
    compute(xb, yb);  prefetch(xb, yb, 5);
    finish_row();     // row 0 done (chunks 0-3 computed)
    compute(xa, ya);  prefetch(xa, ya, 6);
    compute(xb, yb);  prefetch(xb, yb, 7);
    compute(xa, ya);
    compute(xb, yb);
    finish_row();     // row 1 done

    __shared__ float sacc[WPB];
    if (lane == 0) sacc[wave] = wacc;
    __syncthreads();
    if (threadIdx.x == 0) {
        float b = 0.0f;
#pragma unroll
        for (int w = 0; w < WPB; ++w) b += sacc[w];
        partial[blockIdx.x] = b;
    }
}

__global__ __launch_bounds__(BLOCK) void pdl_reduce(const float* __restrict__ partial,
                                                    float* __restrict__ out,
                                                    int n_partial, float inv_n) {
    const float4* p4 = (const float4*)partial;
    float s = 0.0f;
    for (int i = threadIdx.x; i < n_partial / 4; i += BLOCK) {
        const float4 v = p4[i];
        s += (v.x + v.y) + (v.z + v.w);
    }
#pragma unroll
    for (int off = 32; off >= 1; off >>= 1) s += __shfl_down(s, off, 64);
    __shared__ float sw[WPB];
    const int lane = threadIdx.x & 63;
    const int wave = threadIdx.x >> 6;
    if (lane == 0) sw[wave] = s;
    __syncthreads();
    if (threadIdx.x == 0) {
        float t = 0.0f;
#pragma unroll
        for (int w = 0; w < WPB; ++w) t += sw[w];
        out[0] = t * inv_n;
    }
}

extern "C" void kernel_launch(void* const* d_in, const int* in_sizes, int n_in,
                              void* d_out, int out_size, void* d_ws, size_t ws_size,
                              hipStream_t stream) {
    const float* x = (const float*)d_in[0];
    const int*   y = (const int*)d_in[1];
    float* out = (float*)d_out;
    float* partial = (float*)d_ws;  // NBLK floats, fully rewritten each call

    const int n_rows = in_sizes[0] / C_DIM;  // 16384

    pdl_rows<<<NBLK, BLOCK, 0, stream>>>(x, y, partial);
    pdl_reduce<<<1, BLOCK, 0, stream>>>(partial, out, NBLK, 1.0f / (float)n_rows);
}